// Round 12
// baseline (243.309 us; speedup 1.0000x reference)
//
#include <hip/hip_runtime.h>

// Problem constants (B=2, S=2048, D=2048), all tile-divisible.
#define DM  2048
#define SQ  2048
#define NB  2
#define BSZ (NB * SQ)   // 4096 flattened tokens

typedef _Float16 f16x8 __attribute__((ext_vector_type(8)));
typedef __attribute__((ext_vector_type(4))) float f32x4;

#define ASG(p) (const __attribute__((address_space(1))) void*)(p)
#define ASL(p) (__attribute__((address_space(3))) void*)(p)

__device__ __forceinline__ unsigned short f2h(float f) {
  union { _Float16 h; unsigned short u; } x;
  x.h = (_Float16)f;  // v_cvt_f16_f32, RNE
  return x.u;
}
__device__ __forceinline__ float h2f(unsigned short u) {
  union { unsigned short u; _Float16 h; } x;
  x.u = u;
  return (float)x.h;
}

// ---- fused fp32 -> fp16 cast: x (n4x float4s) then Wq,Wk,Wv,Wo (n4w each),
// writing one contiguous fp16 region (x16 | wq | wk | wv | wo). 1 launch.
__global__ __launch_bounds__(256) void cast_all(const float4* __restrict__ x,
                                                const float4* __restrict__ wq,
                                                const float4* __restrict__ wk,
                                                const float4* __restrict__ wv,
                                                const float4* __restrict__ wo,
                                                ushort4* __restrict__ out,
                                                int n4x, int n4w) {
  int i = blockIdx.x * 256 + threadIdx.x;
  float4 v;
  if (i < n4x) {
    v = x[i];
  } else {
    int j = i - n4x;
    int seg = j >> 20;          // n4w == 2^20
    int off = j & (n4w - 1);
    const float4* src = (seg == 0) ? wq : (seg == 1) ? wk : (seg == 2) ? wv : wo;
    v = src[off];
  }
  ushort4 h;
  h.x = f2h(v.x); h.y = f2h(v.y); h.z = f2h(v.z); h.w = f2h(v.w);
  out[i] = h;
}

#define SB() __builtin_amdgcn_sched_barrier(0)
#define BARX() do { SB(); __builtin_amdgcn_s_barrier(); SB(); } while (0)

// ============================================================================
// 128x128 GEMM engine (R12): R11 geometry + staging/vmcnt ledger EXACTLY,
// with MFMA clusters shifted ONE WINDOW LATER so every frag ds_read is issued
// >= 1 full MFMA cluster + barrier before its consuming lgkmcnt — the LDS
// pipe drains under the matrix pipe instead of serializing with it.
// 256 thr = 4 waves (2Mx2N), per-wave 64x64, BK=64, dbuf 2x32KB LDS,
// XOR swizzle (16B slot ^= row&7) both-sides. Stage units = 4KB.
// Steady-state windows for tile T (buf L, a0-set P):
//   W2: read b1;            PH(a0[P],b0) ; BAR     (lgkm waits a0,b0: issued W1')
//   W3: stage A(T+2)->L;    PH(a1,b0)    ; BAR     (a1 issued W1', 2 clusters ago)
//   W4: stage B01(T+2)->L;  PH(a1,b1)    ; [vmcnt] BAR   (b1 issued W2)
//   W1': read a0[P^1],b0,a1 of T+1 from L^1; stage B23(T+2)->L;
//        PH(a0[P],b1)       ; BAR                  (reads interleave under PH)
// Shared-reg liveness: b0/a1/b1 single-buffered (last use W3/W4/W1' before
// next-tile overwrite in W1'/W1'/W2, in-order per wave); a0 double (a0f[2]).
// Stage points + issue order + counts == R11 -> vmcnt(6)/(0) ledger identical.
// Hazards per LDS unit: A-units of L overwritten at W3(T) — reads issued
// W1'(T-1), drained by W3's PH lgkm (same pattern as verified R11). B01(L) at
// W4(T) vs b0 reads W1'(T-1) ✓. B23(T+2)->L at W1'(T) vs b1(T) reads W2(T),
// drained W4(T) ✓. T+1 frag reads at W1'(T) occur AFTER the boundary vmcnt
// completing tile T+1 ✓.
// CAUSAL: 1 = skip blocks bn0 > bm0 (scores), 2 = K-limit NT=(bm0+128)/64.
// ============================================================================
#define STAGEK(BUFL, REG, U, T) do { \
    const unsigned short* G_ = (REG) ? Bb : Ab; \
    const int ldG_ = (REG) ? ldB : ldA; \
    const int r0_ = ((REG) ? bn0 : bm0) + (U) * 32; \
    const long k0_ = (long)((T) << 6); \
    char* db_ = ldsb + (BUFL) * 32768 + (REG) * 16384 + (U) * 4096 + tid * 16; \
    const unsigned short* s_ = G_ + (long)(r0_ + srow) * ldG_ + k0_ + scsw; \
    __builtin_amdgcn_global_load_lds(ASG(s_), ASL(db_), 16, 0, 0); \
  } while (0)

#define LDAK(BUFL, MH, Af) do { \
    const char* ba_ = ldsb + (BUFL) * 32768 + (wm * 64 + (MH) * 32) * 128 + arow; \
    _Pragma("unroll") for (int mm_ = 0; mm_ < 2; mm_++) { \
      Af[mm_][0] = *(const f16x8*)(ba_ + mm_ * 2048 + sl0); \
      Af[mm_][1] = *(const f16x8*)(ba_ + mm_ * 2048 + sl1); } \
  } while (0)

#define LDBK(BUFL, NH, Bf) do { \
    const char* bb_ = ldsb + (BUFL) * 32768 + 16384 + (wn * 64 + (NH) * 32) * 128 + arow; \
    _Pragma("unroll") for (int nn_ = 0; nn_ < 2; nn_++) { \
      Bf[nn_][0] = *(const f16x8*)(bb_ + nn_ * 2048 + sl0); \
      Bf[nn_][1] = *(const f16x8*)(bb_ + nn_ * 2048 + sl1); } \
  } while (0)

#define PHK(Af, Bf, MH, NH) do { \
    __builtin_amdgcn_s_setprio(1); \
    _Pragma("unroll") for (int mm_ = 0; mm_ < 2; mm_++) \
    _Pragma("unroll") for (int nn_ = 0; nn_ < 2; nn_++) \
    _Pragma("unroll") for (int ks_ = 0; ks_ < 2; ks_++) \
      acc[(MH) * 2 + mm_][(NH) * 2 + nn_] = __builtin_amdgcn_mfma_f32_16x16x32_f16( \
          Af[mm_][ks_], Bf[nn_][ks_], acc[(MH) * 2 + mm_][(NH) * 2 + nn_], 0, 0, 0); \
    __builtin_amdgcn_s_setprio(0); \
  } while (0)

// One tile, shifted-cluster schedule. P = a0 set parity of tile T.
#define GROUPF(BUFL, T, P) do { \
    /* W2 */ \
    LDBK(BUFL, 1, b1); \
    PHK(a0f[P], b0, 0, 0); \
    BARX(); \
    /* W3 */ \
    if ((T) + 2 < NT) { STAGEK(BUFL, 0, 0, (T) + 2); STAGEK(BUFL, 0, 1, (T) + 2); \
                        STAGEK(BUFL, 0, 2, (T) + 2); STAGEK(BUFL, 0, 3, (T) + 2); } \
    PHK(a1, b0, 1, 0); \
    BARX(); \
    /* W4 */ \
    if ((T) + 2 < NT) { STAGEK(BUFL, 1, 0, (T) + 2); STAGEK(BUFL, 1, 1, (T) + 2); } \
    PHK(a1, b1, 1, 1); \
    SB(); \
    if ((T) + 1 < NT) { \
      if ((T) + 1 == NT - 1) { asm volatile("s_waitcnt vmcnt(0)" ::: "memory"); } \
      else                   { asm volatile("s_waitcnt vmcnt(6)" ::: "memory"); } \
    } \
    __builtin_amdgcn_s_barrier(); \
    SB(); \
    /* W1' : next tile's frag reads + B23 stage, under this tile's last PH */ \
    if ((T) + 1 < NT) { \
      LDAK((BUFL) ^ 1, 0, a0f[(P) ^ 1]); LDBK((BUFL) ^ 1, 0, b0); LDAK((BUFL) ^ 1, 1, a1); \
      if ((T) + 2 < NT) { STAGEK(BUFL, 1, 2, (T) + 2); STAGEK(BUFL, 1, 3, (T) + 2); } \
    } \
    PHK(a0f[P], b1, 0, 1); \
    BARX(); \
  } while (0)

template <int OM, int CAUSAL>
__global__ __launch_bounds__(256, 2) void gemm128(
    const unsigned short* __restrict__ A, const unsigned short* __restrict__ B,
    float* __restrict__ Cf, unsigned short* __restrict__ Ch,
    int K, long sAb, long sBb, long sCb,
    int ldA, int ldB, int ldC, float alpha) {
  __shared__ __align__(16) char ldsarr[65536];
  char* ldsb = ldsarr;

  const int bm0 = blockIdx.x * 128;
  const int bn0 = blockIdx.y * 128;
  if (CAUSAL == 1 && bn0 > bm0) return;  // fully masked; never read later

  const int z = blockIdx.z;
  const unsigned short* Ab = A + (long)z * sAb;
  const unsigned short* Bb = B + (long)z * sBb;
  const long cb = (long)z * sCb;

  const int tid = threadIdx.x, lane = tid & 63, wid = tid >> 6;
  const int wm = wid >> 1, wn = wid & 1;
  const int fr = lane & 15, fq = lane >> 4;
  int NT = K >> 6;
  if (CAUSAL == 2) NT = (bm0 + 128) >> 6;  // even; >=2

  // ds_read swizzled slot addresses (row&7 == fr&7 for fragment rows)
  const int sl0 = ((fq ^ (fr & 7)) << 4);
  const int sl1 = (((4 + fq) ^ (fr & 7)) << 4);
  const int arow = fr << 7;

  // staging: 256 thr x 16B = 4KB unit = 32 rows x 128B; 8 thr/row
  const int srow = tid >> 3;                       // [0,32)
  const int scsw = ((tid & 7) ^ (srow & 7)) << 3;  // inverse-swizzled global col

  f32x4 acc[4][4];
#pragma unroll
  for (int m = 0; m < 4; m++)
#pragma unroll
    for (int n = 0; n < 4; n++)
#pragma unroll
      for (int r = 0; r < 4; r++) acc[m][n][r] = 0.f;

  f16x8 a0f[2][2][2], a1[2][2], b0[2][2], b1[2][2];

  // Prologue stages (R11 exact): tile0 all 8 units + tile1 A0..A3, B0,B1.
  STAGEK(0, 0, 0, 0); STAGEK(0, 0, 1, 0); STAGEK(0, 0, 2, 0); STAGEK(0, 0, 3, 0);
  STAGEK(0, 1, 0, 0); STAGEK(0, 1, 1, 0); STAGEK(0, 1, 2, 0); STAGEK(0, 1, 3, 0);
  STAGEK(1, 0, 0, 1); STAGEK(1, 0, 1, 1); STAGEK(1, 0, 2, 1); STAGEK(1, 0, 3, 1);
  STAGEK(1, 1, 0, 1); STAGEK(1, 1, 1, 1);
  asm volatile("s_waitcnt vmcnt(6)" ::: "memory");
  __builtin_amdgcn_s_barrier();
  SB();

  // Peeled W1(0): tile0 frag reads into set 0 + stage B23(1)->buf1 (NT>=2).
  LDAK(0, 0, a0f[0]); LDBK(0, 0, b0); LDAK(0, 1, a1);
  STAGEK(1, 1, 2, 1); STAGEK(1, 1, 3, 1);
  BARX();

  for (int t = 0; t < NT; t += 2) {
    GROUPF(0, t, 0);
    GROUPF(1, t + 1, 1);
  }

  // Epilogue: row = bm0 + wm*64 + mh*32 + mm*16 + fq*4 + r,
  //           col = bn0 + wn*64 + nh*32 + nn*16 + fr
#pragma unroll
  for (int mh = 0; mh < 2; mh++)
#pragma unroll
    for (int mm = 0; mm < 2; mm++)
#pragma unroll
      for (int nh = 0; nh < 2; nh++)
#pragma unroll
        for (int nn = 0; nn < 2; nn++) {
          const int col = bn0 + wn * 64 + nh * 32 + nn * 16 + fr;
#pragma unroll
          for (int r = 0; r < 4; r++) {
            const long row = (long)bm0 + wm * 64 + mh * 32 + mm * 16 + fq * 4 + r;
            const long ci = cb + row * ldC + col;
            const float vv = acc[mh * 2 + mm][nh * 2 + nn][r] * alpha;
            if constexpr (OM == 0) Cf[ci] = vv;
            else                   Ch[ci] = f2h(vv);
          }
        }
}

// ---- causal row softmax: scores fp16 [NB*SQ][SQ] -> probs fp16, zeros t>s.
// Vectorized: each thread owns 8 contiguous fp16 (one 16B load/store).
__global__ __launch_bounds__(256) void softmax_causal(const unsigned short* __restrict__ sc,
                                                      unsigned short* __restrict__ pr) {
  const int row = blockIdx.x;       // b*SQ + s
  const int s = row & (SQ - 1);
  const long base = (long)row * SQ;
  const int n = s + 1;              // valid prefix length
  const int tid = threadIdx.x;
  const int lane = tid & 63;
  const int wv = tid >> 6;
  const int e0 = tid * 8;           // this thread's first element
  __shared__ float red[4];

  union { uint4 u4; unsigned short us[8]; } in, ou;
  in.u4 = *(const uint4*)&sc[base + e0];

  float v[8];
  float mx = -3.0e38f;
#pragma unroll
  for (int j = 0; j < 8; j++) {
    v[j] = (e0 + j < n) ? h2f(in.us[j]) : -3.0e38f;  // mask BEFORE use
    mx = fmaxf(mx, v[j]);
  }
#pragma unroll
  for (int o = 32; o >= 1; o >>= 1) mx = fmaxf(mx, __shfl_xor(mx, o));
  if (lane == 0) red[wv] = mx;
  __syncthreads();
  mx = fmaxf(fmaxf(red[0], red[1]), fmaxf(red[2], red[3]));
  __syncthreads();

  float sum = 0.f;
#pragma unroll
  for (int j = 0; j < 8; j++) {
    v[j] = (e0 + j < n) ? __expf(v[j] - mx) : 0.f;
    sum += v[j];
  }
#pragma unroll
  for (int o = 32; o >= 1; o >>= 1) sum += __shfl_xor(sum, o);
  if (lane == 0) red[wv] = sum;
  __syncthreads();
  const float inv = 1.f / (red[0] + red[1] + red[2] + red[3]);
#pragma unroll
  for (int j = 0; j < 8; j++) ou.us[j] = (e0 + j < n) ? f2h(v[j] * inv) : (unsigned short)0;
  *(uint4*)&pr[base + e0] = ou.u4;
}

extern "C" void kernel_launch(void* const* d_in, const int* in_sizes, int n_in,
                              void* d_out, int out_size, void* d_ws, size_t ws_size,
                              hipStream_t stream) {
  (void)in_sizes; (void)n_in; (void)out_size; (void)ws_size;
  const float* x  = (const float*)d_in[0];
  // d_in[1] = mask: exactly causal-additive(-1e9) -> implemented structurally.
  const float* Wq = (const float*)d_in[2];
  const float* Wk = (const float*)d_in[3];
  const float* Wv = (const float*)d_in[4];
  const float* Wo = (const float*)d_in[5];
  float* out = (float*)d_out;

  const long ELx = (long)BSZ * DM;  // 8,388,608
  const long ELw = (long)DM * DM;   // 4,194,304

  char* ws = (char*)d_ws;
  size_t off = 0;
  auto take = [&](size_t bytes) { void* p = ws + off; off += bytes; return p; };

  unsigned short* x16   = (unsigned short*)take(ELx * 2);      // dead after vTT
  unsigned short* wqk16 = (unsigned short*)take(2 * ELw * 2);  // [Wq;Wk]; dead after QK
  unsigned short* wv16  = (unsigned short*)take(ELw * 2);      // dead after vTT
  unsigned short* wo16  = (unsigned short*)take(ELw * 2);
  unsigned short* qk16  = (unsigned short*)take((long)BSZ * 2 * DM * 2);  // [4096][4096]
  unsigned short* vTT   = (unsigned short*)take(ELx * 2);      // [2048 d][4096 tok]
  unsigned short* probs = (unsigned short*)take((long)NB * SQ * SQ * 2);
  // scores fp16 (16.8MB) aliases x16 exactly (x dead after vTT GEMM);
  // ctx (16.8MB fp16) aliases qk16 (dead after scores GEMM).
  unsigned short* scores = x16;
  unsigned short* ctx = qk16;
  unsigned short* q16 = qk16;         // ld 4096
  unsigned short* k16 = qk16 + DM;    // ld 4096

  const int n4x = (int)(ELx / 4), n4w = (int)(ELw / 4);
  // x16|wqk16|wv16|wo16 are one contiguous fp16 region -> single fused cast.
  cast_all<<<dim3((n4x + 4 * n4w) / 256), 256, 0, stream>>>(
      (const float4*)x, (const float4*)Wq, (const float4*)Wk,
      (const float4*)Wv, (const float4*)Wo, (ushort4*)x16, n4x, n4w);

  const float scale = 0.08838834764831845f;  // 1/sqrt(128)

  // qk = x @ [Wq;Wk]^T   [4096 x 4096], 32x32 = 1024 blocks (2/CU)
  gemm128<1, 0><<<dim3(BSZ / 128, 2 * DM / 128, 1), 256, 0, stream>>>(
      x16, wqk16, nullptr, qk16, DM, 0L, 0L, 0L, DM, DM, 2 * DM, 1.0f);
  // vTT[d][tok] = Wv @ x^T   [2048 x 4096], 16x32 = 512 blocks (2/CU)
  gemm128<1, 0><<<dim3(DM / 128, BSZ / 128, 1), 256, 0, stream>>>(
      wv16, x16, nullptr, vTT, DM, 0L, 0L, 0L, DM, DM, BSZ, 1.0f);
  // scores[b][s][t] = scale * q.k   (fp16 out, causal block-skip)
  gemm128<1, 1><<<dim3(SQ / 128, SQ / 128, NB), 256, 0, stream>>>(
      q16, k16, nullptr, scores, DM, (long)SQ * 2 * DM, (long)SQ * 2 * DM,
      (long)SQ * SQ, 2 * DM, 2 * DM, SQ, scale);

  softmax_causal<<<dim3(NB * SQ), 256, 0, stream>>>(scores, probs);

  // ctx[b][s][d] = sum_t P[b][s][t] * vTT[d][b*2048+t]   (K-limited)
  gemm128<1, 2><<<dim3(SQ / 128, DM / 128, NB), 256, 0, stream>>>(
      probs, vTT, nullptr, ctx, SQ, (long)SQ * SQ, 2048L, (long)SQ * DM,
      SQ, BSZ, DM, 1.0f);
  // out = ctx @ Wo^T   (fp32 out)  [4096 x 2048], 32x16 = 512 blocks
  gemm128<0, 0><<<dim3(BSZ / 128, DM / 128, 1), 256, 0, stream>>>(
      ctx, wo16, out, nullptr, DM, 0L, 0L, 0L, DM, DM, DM, 1.0f);
}

// Round 13
// 237.055 us; speedup vs baseline: 1.0264x; 1.0264x over previous
//
#include <hip/hip_runtime.h>

// Problem constants (B=2, S=2048, D=2048), all tile-divisible.
#define DM  2048
#define SQ  2048
#define NB  2
#define BSZ (NB * SQ)   // 4096 flattened tokens

typedef _Float16 f16x8 __attribute__((ext_vector_type(8)));
typedef __attribute__((ext_vector_type(4))) float f32x4;

#define ASG(p) (const __attribute__((address_space(1))) void*)(p)
#define ASL(p) (__attribute__((address_space(3))) void*)(p)

__device__ __forceinline__ unsigned short f2h(float f) {
  union { _Float16 h; unsigned short u; } x;
  x.h = (_Float16)f;  // v_cvt_f16_f32, RNE
  return x.u;
}
__device__ __forceinline__ float h2f(unsigned short u) {
  union { unsigned short u; _Float16 h; } x;
  x.u = u;
  return (float)x.h;
}

// ---- fused fp32 -> fp16 cast: x (n4x float4s) then Wq,Wk,Wv,Wo (n4w each),
// writing one contiguous fp16 region (x16 | wq | wk | wv | wo). 1 launch.
__global__ __launch_bounds__(256) void cast_all(const float4* __restrict__ x,
                                                const float4* __restrict__ wq,
                                                const float4* __restrict__ wk,
                                                const float4* __restrict__ wv,
                                                const float4* __restrict__ wo,
                                                ushort4* __restrict__ out,
                                                int n4x, int n4w) {
  int i = blockIdx.x * 256 + threadIdx.x;
  float4 v;
  if (i < n4x) {
    v = x[i];
  } else {
    int j = i - n4x;
    int seg = j >> 20;          // n4w == 2^20
    int off = j & (n4w - 1);
    const float4* src = (seg == 0) ? wq : (seg == 1) ? wk : (seg == 2) ? wv : wo;
    v = src[off];
  }
  ushort4 h;
  h.x = f2h(v.x); h.y = f2h(v.y); h.z = f2h(v.z); h.w = f2h(v.w);
  out[i] = h;
}

#define SB() __builtin_amdgcn_sched_barrier(0)
#define BARX() do { SB(); __builtin_amdgcn_s_barrier(); SB(); } while (0)

// ============================================================================
// 128x128 GEMM engine body (R11 schedule EXACTLY — verified race-free,
// best measured). 256 thr = 4 waves (2Mx2N), per-wave 64x64, BK=64,
// dbuf 2x32KB LDS, XOR swizzle (16B slot ^= row&7) both-sides (rule #21).
// Stage units = 4KB. Windows per tile t (buffer L):
//   W1{read a0,b0,a1; stage B2,B3(t+1)->L^1; PH(a0b0)} BAR
//   W2{read b1; PH(a1b0)} BAR
//   W3{stage A0..A3(t+2)->L; PH(a1b1)} BAR
//   W4{stage B0,B1(t+2)->L; PH(a0b1)} [vmcnt] BAR
// Hazards + vmcnt(6)/(0) ledger as verified in R11 (see R11 commentary).
// ============================================================================
#define STAGEK(BUFL, REG, U, T) do { \
    const unsigned short* G_ = (REG) ? Bb : Ab; \
    const int ldG_ = (REG) ? ldB : ldA; \
    const int r0_ = ((REG) ? bn0 : bm0) + (U) * 32; \
    const long k0_ = (long)((T) << 6); \
    char* db_ = ldsb + (BUFL) * 32768 + (REG) * 16384 + (U) * 4096 + tid * 16; \
    const unsigned short* s_ = G_ + (long)(r0_ + srow) * ldG_ + k0_ + scsw; \
    __builtin_amdgcn_global_load_lds(ASG(s_), ASL(db_), 16, 0, 0); \
  } while (0)

#define LDAK(BUFL, MH, Af) do { \
    const char* ba_ = ldsb + (BUFL) * 32768 + (wm * 64 + (MH) * 32) * 128 + arow; \
    _Pragma("unroll") for (int mm_ = 0; mm_ < 2; mm_++) { \
      Af[mm_][0] = *(const f16x8*)(ba_ + mm_ * 2048 + sl0); \
      Af[mm_][1] = *(const f16x8*)(ba_ + mm_ * 2048 + sl1); } \
  } while (0)

#define LDBK(BUFL, NH, Bf) do { \
    const char* bb_ = ldsb + (BUFL) * 32768 + 16384 + (wn * 64 + (NH) * 32) * 128 + arow; \
    _Pragma("unroll") for (int nn_ = 0; nn_ < 2; nn_++) { \
      Bf[nn_][0] = *(const f16x8*)(bb_ + nn_ * 2048 + sl0); \
      Bf[nn_][1] = *(const f16x8*)(bb_ + nn_ * 2048 + sl1); } \
  } while (0)

#define PHK(Af, Bf, MH, NH) do { \
    __builtin_amdgcn_s_setprio(1); \
    _Pragma("unroll") for (int mm_ = 0; mm_ < 2; mm_++) \
    _Pragma("unroll") for (int nn_ = 0; nn_ < 2; nn_++) \
    _Pragma("unroll") for (int ks_ = 0; ks_ < 2; ks_++) \
      acc[(MH) * 2 + mm_][(NH) * 2 + nn_] = __builtin_amdgcn_mfma_f32_16x16x32_f16( \
          Af[mm_][ks_], Bf[nn_][ks_], acc[(MH) * 2 + mm_][(NH) * 2 + nn_], 0, 0, 0); \
    __builtin_amdgcn_s_setprio(0); \
  } while (0)

#define GROUPK(BUFL, T) do { \
    LDAK(BUFL, 0, a0); LDBK(BUFL, 0, b0); \
    LDAK(BUFL, 1, a1); \
    if ((T) + 1 < NT) { STAGEK((BUFL) ^ 1, 1, 2, (T) + 1); STAGEK((BUFL) ^ 1, 1, 3, (T) + 1); } \
    PHK(a0, b0, 0, 0); \
    BARX(); \
    LDBK(BUFL, 1, b1); \
    PHK(a1, b0, 1, 0); \
    BARX(); \
    if ((T) + 2 < NT) { STAGEK(BUFL, 0, 0, (T) + 2); STAGEK(BUFL, 0, 1, (T) + 2); \
                        STAGEK(BUFL, 0, 2, (T) + 2); STAGEK(BUFL, 0, 3, (T) + 2); } \
    PHK(a1, b1, 1, 1); \
    BARX(); \
    if ((T) + 2 < NT) { STAGEK(BUFL, 1, 0, (T) + 2); STAGEK(BUFL, 1, 1, (T) + 2); } \
    PHK(a0, b1, 0, 1); \
    SB(); \
    if ((T) + 1 < NT) { \
      if ((T) + 1 == NT - 1) { asm volatile("s_waitcnt vmcnt(0)" ::: "memory"); } \
      else                   { asm volatile("s_waitcnt vmcnt(6)" ::: "memory"); } \
    } \
    __builtin_amdgcn_s_barrier(); \
    SB(); \
  } while (0)

template <int OM>
__device__ __forceinline__ void gemm128_body(
    char* ldsb, const unsigned short* __restrict__ Ab,
    const unsigned short* __restrict__ Bb,
    float* __restrict__ Cf, unsigned short* __restrict__ Ch, long cb,
    int NT, int ldA, int ldB, int ldC, int bm0, int bn0, float alpha) {
  const int tid = threadIdx.x, lane = tid & 63, wid = tid >> 6;
  const int wm = wid >> 1, wn = wid & 1;
  const int fr = lane & 15, fq = lane >> 4;

  // ds_read swizzled slot addresses (row&7 == fr&7 for fragment rows)
  const int sl0 = ((fq ^ (fr & 7)) << 4);
  const int sl1 = (((4 + fq) ^ (fr & 7)) << 4);
  const int arow = fr << 7;

  // staging: 256 thr x 16B = 4KB unit = 32 rows x 128B; 8 thr/row
  const int srow = tid >> 3;                       // [0,32)
  const int scsw = ((tid & 7) ^ (srow & 7)) << 3;  // inverse-swizzled global col

  f32x4 acc[4][4];
#pragma unroll
  for (int m = 0; m < 4; m++)
#pragma unroll
    for (int n = 0; n < 4; n++)
#pragma unroll
      for (int r = 0; r < 4; r++) acc[m][n][r] = 0.f;

  f16x8 a0[2][2], a1[2][2], b0[2][2], b1[2][2];

  // Prologue: tile0 all 8 units + tile1 A0..A3, B0,B1 (NT>=2 always).
  STAGEK(0, 0, 0, 0); STAGEK(0, 0, 1, 0); STAGEK(0, 0, 2, 0); STAGEK(0, 0, 3, 0);
  STAGEK(0, 1, 0, 0); STAGEK(0, 1, 1, 0); STAGEK(0, 1, 2, 0); STAGEK(0, 1, 3, 0);
  STAGEK(1, 0, 0, 1); STAGEK(1, 0, 1, 1); STAGEK(1, 0, 2, 1); STAGEK(1, 0, 3, 1);
  STAGEK(1, 1, 0, 1); STAGEK(1, 1, 1, 1);
  asm volatile("s_waitcnt vmcnt(6)" ::: "memory");
  __builtin_amdgcn_s_barrier();
  SB();

  for (int t = 0; t < NT; t += 2) {
    GROUPK(0, t);
    GROUPK(1, t + 1);
  }

  // Epilogue: row = bm0 + wm*64 + mh*32 + mm*16 + fq*4 + r,
  //           col = bn0 + wn*64 + nh*32 + nn*16 + fr
#pragma unroll
  for (int mh = 0; mh < 2; mh++)
#pragma unroll
    for (int mm = 0; mm < 2; mm++)
#pragma unroll
      for (int nh = 0; nh < 2; nh++)
#pragma unroll
        for (int nn = 0; nn < 2; nn++) {
          const int col = bn0 + wn * 64 + nh * 32 + nn * 16 + fr;
#pragma unroll
          for (int r = 0; r < 4; r++) {
            const long row = (long)bm0 + wm * 64 + mh * 32 + mm * 16 + fq * 4 + r;
            const long ci = cb + row * ldC + col;
            const float vv = acc[mh * 2 + mm][nh * 2 + nn][r] * alpha;
            if constexpr (OM == 0) Cf[ci] = vv;
            else                   Ch[ci] = f2h(vv);
          }
        }
}

// Standalone wrapper (QK / PV / O). CAUSAL: 0 none, 2 = K-limit NT=(bm0+128)/64.
template <int OM, int CAUSAL>
__global__ __launch_bounds__(256, 2) void gemm128(
    const unsigned short* __restrict__ A, const unsigned short* __restrict__ B,
    float* __restrict__ Cf, unsigned short* __restrict__ Ch,
    int K, long sAb, long sBb, long sCb,
    int ldA, int ldB, int ldC, float alpha) {
  __shared__ __align__(16) char ldsarr[65536];
  const int bm0 = blockIdx.x * 128;
  const int bn0 = blockIdx.y * 128;
  const int z = blockIdx.z;
  int NT = K >> 6;
  if (CAUSAL == 2) NT = (bm0 + 128) >> 6;  // even; >=2
  gemm128_body<OM>(ldsarr, A + (long)z * sAb, B + (long)z * sBb,
                   Cf, Ch, (long)z * sCb, NT, ldA, ldB, ldC, bm0, bn0, alpha);
}

// Merged dispatch: scores (z<2, y<16, causal block-skip) || vTT (z==2).
// scores: [b][s][t] = scale * q.k (fp16 out). vTT: [d][tok] = Wv @ x^T.
// No data overlap: scores reads qk16 / writes scoresBuf; vTT reads wv16,x16 /
// writes vTT. 784 active blocks over 512 CU-slots -> backfills the 240 idle
// slots the standalone scores dispatch leaves.
__global__ __launch_bounds__(256, 2) void k_scores_vtt(
    const unsigned short* __restrict__ qk, unsigned short* __restrict__ scores,
    const unsigned short* __restrict__ wv, const unsigned short* __restrict__ x16,
    unsigned short* __restrict__ vTT, float scale) {
  __shared__ __align__(16) char ldsarr[65536];
  const int bm0 = blockIdx.x * 128;
  const int bn0 = blockIdx.y * 128;
  if (blockIdx.z < 2) {
    if (blockIdx.y >= SQ / 128) return;   // scores grid is 16x16
    if (bn0 > bm0) return;                // fully masked; never read later
    const long z = blockIdx.z;
    gemm128_body<1>(ldsarr, qk + z * (long)SQ * 2 * DM, qk + DM + z * (long)SQ * 2 * DM,
                    nullptr, scores, z * (long)SQ * SQ,
                    DM >> 6, 2 * DM, 2 * DM, SQ, bm0, bn0, scale);
  } else {
    gemm128_body<1>(ldsarr, wv, x16, nullptr, vTT, 0L,
                    DM >> 6, DM, DM, BSZ, bm0, bn0, 1.0f);
  }
}

// ---- causal row softmax: scores fp16 [NB*SQ][SQ] -> probs fp16, zeros t>s.
// Vectorized: each thread owns 8 contiguous fp16 (one 16B load/store).
__global__ __launch_bounds__(256) void softmax_causal(const unsigned short* __restrict__ sc,
                                                      unsigned short* __restrict__ pr) {
  const int row = blockIdx.x;       // b*SQ + s
  const int s = row & (SQ - 1);
  const long base = (long)row * SQ;
  const int n = s + 1;              // valid prefix length
  const int tid = threadIdx.x;
  const int lane = tid & 63;
  const int wv = tid >> 6;
  const int e0 = tid * 8;           // this thread's first element
  __shared__ float red[4];

  union { uint4 u4; unsigned short us[8]; } in, ou;
  in.u4 = *(const uint4*)&sc[base + e0];

  float v[8];
  float mx = -3.0e38f;
#pragma unroll
  for (int j = 0; j < 8; j++) {
    v[j] = (e0 + j < n) ? h2f(in.us[j]) : -3.0e38f;  // mask BEFORE use
    mx = fmaxf(mx, v[j]);
  }
#pragma unroll
  for (int o = 32; o >= 1; o >>= 1) mx = fmaxf(mx, __shfl_xor(mx, o));
  if (lane == 0) red[wv] = mx;
  __syncthreads();
  mx = fmaxf(fmaxf(red[0], red[1]), fmaxf(red[2], red[3]));
  __syncthreads();

  float sum = 0.f;
#pragma unroll
  for (int j = 0; j < 8; j++) {
    v[j] = (e0 + j < n) ? __expf(v[j] - mx) : 0.f;
    sum += v[j];
  }
#pragma unroll
  for (int o = 32; o >= 1; o >>= 1) sum += __shfl_xor(sum, o);
  if (lane == 0) red[wv] = sum;
  __syncthreads();
  const float inv = 1.f / (red[0] + red[1] + red[2] + red[3]);
#pragma unroll
  for (int j = 0; j < 8; j++) ou.us[j] = (e0 + j < n) ? f2h(v[j] * inv) : (unsigned short)0;
  *(uint4*)&pr[base + e0] = ou.u4;
}

extern "C" void kernel_launch(void* const* d_in, const int* in_sizes, int n_in,
                              void* d_out, int out_size, void* d_ws, size_t ws_size,
                              hipStream_t stream) {
  (void)in_sizes; (void)n_in; (void)out_size; (void)ws_size;
  const float* x  = (const float*)d_in[0];
  // d_in[1] = mask: exactly causal-additive(-1e9) -> implemented structurally.
  const float* Wq = (const float*)d_in[2];
  const float* Wk = (const float*)d_in[3];
  const float* Wv = (const float*)d_in[4];
  const float* Wo = (const float*)d_in[5];
  float* out = (float*)d_out;

  const long ELx = (long)BSZ * DM;  // 8,388,608
  const long ELw = (long)DM * DM;   // 4,194,304

  char* ws = (char*)d_ws;
  size_t off = 0;
  auto take = [&](size_t bytes) { void* p = ws + off; off += bytes; return p; };

  unsigned short* x16   = (unsigned short*)take(ELx * 2);      // live through merged launch
  unsigned short* wqk16 = (unsigned short*)take(2 * ELw * 2);  // [Wq;Wk]; dead after QK
  unsigned short* wv16  = (unsigned short*)take(ELw * 2);      // dead after merged launch
  unsigned short* wo16  = (unsigned short*)take(ELw * 2);
  unsigned short* qk16  = (unsigned short*)take((long)BSZ * 2 * DM * 2);  // [4096][4096]
  unsigned short* vTT   = (unsigned short*)take(ELx * 2);      // [2048 d][4096 tok]
  unsigned short* probs = (unsigned short*)take((long)NB * SQ * SQ * 2);
  // scores fp16 (16.8MB) aliases wqk16 (dead after QK; merged launch is
  // stream-ordered after QK). NOT x16 — vTT reads x16 concurrently.
  // ctx (16.8MB fp16) aliases qk16 (dead after merged launch).
  unsigned short* scores = wqk16;
  unsigned short* ctx = qk16;
  unsigned short* q16 = qk16;         // ld 4096
  unsigned short* k16 = qk16 + DM;    // ld 4096
  (void)q16; (void)k16;

  const int n4x = (int)(ELx / 4), n4w = (int)(ELw / 4);
  // x16|wqk16|wv16|wo16 are one contiguous fp16 region -> single fused cast.
  cast_all<<<dim3((n4x + 4 * n4w) / 256), 256, 0, stream>>>(
      (const float4*)x, (const float4*)Wq, (const float4*)Wk,
      (const float4*)Wv, (const float4*)Wo, (ushort4*)x16, n4x, n4w);

  const float scale = 0.08838834764831845f;  // 1/sqrt(128)

  // qk = x @ [Wq;Wk]^T   [4096 x 4096], 32x32 = 1024 blocks (2/CU)
  gemm128<1, 0><<<dim3(BSZ / 128, 2 * DM / 128, 1), 256, 0, stream>>>(
      x16, wqk16, nullptr, qk16, DM, 0L, 0L, 0L, DM, DM, 2 * DM, 1.0f);

  // scores (causal block-skip, fp16 out, 272 active) || vTT (512 blocks):
  // one dispatch, 784 active blocks -> ~1.53 rounds at 2 blocks/CU.
  k_scores_vtt<<<dim3(SQ / 128, BSZ / 128, 3), 256, 0, stream>>>(
      qk16, scores, wv16, x16, vTT, scale);

  softmax_causal<<<dim3(NB * SQ), 256, 0, stream>>>(scores, probs);

  // ctx[b][s][d] = sum_t P[b][s][t] * vTT[d][b*2048+t]   (K-limited)
  gemm128<1, 2><<<dim3(SQ / 128, DM / 128, NB), 256, 0, stream>>>(
      probs, vTT, nullptr, ctx, SQ, (long)SQ * SQ, 2048L, (long)SQ * DM,
      SQ, BSZ, DM, 1.0f);
  // out = ctx @ Wo^T   (fp32 out)  [4096 x 2048], 32x16 = 512 blocks
  gemm128<0, 0><<<dim3(BSZ / 128, DM / 128, 1), 256, 0, stream>>>(
      ctx, wo16, out, nullptr, DM, 0L, 0L, 0L, DM, DM, DM, 1.0f);
}

// Round 14
// 208.403 us; speedup vs baseline: 1.1675x; 1.1375x over previous
//
#include <hip/hip_runtime.h>

// Problem constants (B=2, S=2048, D=2048), all tile-divisible.
#define DM  2048
#define SQ  2048
#define NB  2
#define BSZ (NB * SQ)   // 4096 flattened tokens

typedef _Float16 f16x8 __attribute__((ext_vector_type(8)));
typedef __attribute__((ext_vector_type(4))) float f32x4;

#define ASG(p) (const __attribute__((address_space(1))) void*)(p)
#define ASL(p) (__attribute__((address_space(3))) void*)(p)

__device__ __forceinline__ unsigned short f2h(float f) {
  union { _Float16 h; unsigned short u; } x;
  x.h = (_Float16)f;  // v_cvt_f16_f32, RNE
  return x.u;
}
__device__ __forceinline__ float h2f(unsigned short u) {
  union { unsigned short u; _Float16 h; } x;
  x.u = u;
  return (float)x.h;
}

// ---- straight fp32->fp16 cast: x (n4x float4s) then Wo (n4w), contiguous out.
__global__ __launch_bounds__(256) void cast_x_wo(const float4* __restrict__ x,
                                                 const float4* __restrict__ wo,
                                                 ushort4* __restrict__ outx,
                                                 ushort4* __restrict__ outwo,
                                                 int n4x, int n4w) {
  int i = blockIdx.x * 256 + threadIdx.x;
  float4 v;
  ushort4* dst;
  int j;
  if (i < n4x) { v = x[i]; dst = outx; j = i; }
  else { j = i - n4x; if (j >= n4w) return; v = wo[j]; dst = outwo; }
  ushort4 h;
  h.x = f2h(v.x); h.y = f2h(v.y); h.z = f2h(v.z); h.w = f2h(v.w);
  dst[j] = h;
}

// ---- transpose-cast: W f32 [2048][2048] (d,e) -> WT fp16 [2048][2048] (e,d).
// 64x64 tiles, 256 threads. z selects {Wq,Wk,Wv}.
__global__ __launch_bounds__(256) void cast_t(const float* __restrict__ wq,
                                              const float* __restrict__ wk,
                                              const float* __restrict__ wv,
                                              unsigned short* __restrict__ wqT,
                                              unsigned short* __restrict__ wkT,
                                              unsigned short* __restrict__ wvT) {
  __shared__ unsigned short tile[64][66];
  const float* in = (blockIdx.z == 0) ? wq : (blockIdx.z == 1) ? wk : wv;
  unsigned short* outT = (blockIdx.z == 0) ? wqT : (blockIdx.z == 1) ? wkT : wvT;
  const int tid = threadIdx.x;
  const int d0 = blockIdx.x * 64, e0 = blockIdx.y * 64;
  const int r = tid >> 4;          // 0..15
  const int c = (tid & 15) * 4;    // 0..60
#pragma unroll
  for (int p = 0; p < 4; p++) {
    const int dl = r + p * 16;
    float4 v = *(const float4*)&in[(long)(d0 + dl) * DM + e0 + c];
    tile[c + 0][dl] = f2h(v.x);
    tile[c + 1][dl] = f2h(v.y);
    tile[c + 2][dl] = f2h(v.z);
    tile[c + 3][dl] = f2h(v.w);
  }
  __syncthreads();
  const int r2 = tid >> 3;         // 0..31
  const int c2 = (tid & 7) * 8;    // 0..56
#pragma unroll
  for (int p = 0; p < 2; p++) {
    const int el = r2 + p * 32;
    union { uint4 u4; unsigned short us[8]; } o;
#pragma unroll
    for (int k = 0; k < 8; k++) o.us[k] = tile[el][c2 + k];
    *(uint4*)&outT[(long)(e0 + el) * DM + d0 + c2] = o.u4;
  }
}

#define SB() __builtin_amdgcn_sched_barrier(0)
#define BARX() do { SB(); __builtin_amdgcn_s_barrier(); SB(); } while (0)

// ============================================================================
// 128x128 GEMM engine body (R11 schedule EXACTLY — verified race-free over
// R11/R12/R13 replays). 256 thr = 4 waves (2Mx2N), per-wave 64x64, BK=64,
// dbuf 2x32KB LDS, XOR swizzle (16B slot ^= row&7) both-sides (rule #21).
// Windows/hazards/vmcnt(6)/(0) ledger: see R11 commentary.
// ============================================================================
#define STAGEK(BUFL, REG, U, T) do { \
    const unsigned short* G_ = (REG) ? Bb : Ab; \
    const int ldG_ = (REG) ? ldB : ldA; \
    const int r0_ = ((REG) ? bn0 : bm0) + (U) * 32; \
    const long k0_ = (long)((T) << 6); \
    char* db_ = ldsb + (BUFL) * 32768 + (REG) * 16384 + (U) * 4096 + tid * 16; \
    const unsigned short* s_ = G_ + (long)(r0_ + srow) * ldG_ + k0_ + scsw; \
    __builtin_amdgcn_global_load_lds(ASG(s_), ASL(db_), 16, 0, 0); \
  } while (0)

#define LDAK(BUFL, MH, Af) do { \
    const char* ba_ = ldsb + (BUFL) * 32768 + (wm * 64 + (MH) * 32) * 128 + arow; \
    _Pragma("unroll") for (int mm_ = 0; mm_ < 2; mm_++) { \
      Af[mm_][0] = *(const f16x8*)(ba_ + mm_ * 2048 + sl0); \
      Af[mm_][1] = *(const f16x8*)(ba_ + mm_ * 2048 + sl1); } \
  } while (0)

#define LDBK(BUFL, NH, Bf) do { \
    const char* bb_ = ldsb + (BUFL) * 32768 + 16384 + (wn * 64 + (NH) * 32) * 128 + arow; \
    _Pragma("unroll") for (int nn_ = 0; nn_ < 2; nn_++) { \
      Bf[nn_][0] = *(const f16x8*)(bb_ + nn_ * 2048 + sl0); \
      Bf[nn_][1] = *(const f16x8*)(bb_ + nn_ * 2048 + sl1); } \
  } while (0)

#define PHK(Af, Bf, MH, NH) do { \
    __builtin_amdgcn_s_setprio(1); \
    _Pragma("unroll") for (int mm_ = 0; mm_ < 2; mm_++) \
    _Pragma("unroll") for (int nn_ = 0; nn_ < 2; nn_++) \
    _Pragma("unroll") for (int ks_ = 0; ks_ < 2; ks_++) \
      acc[(MH) * 2 + mm_][(NH) * 2 + nn_] = __builtin_amdgcn_mfma_f32_16x16x32_f16( \
          Af[mm_][ks_], Bf[nn_][ks_], acc[(MH) * 2 + mm_][(NH) * 2 + nn_], 0, 0, 0); \
    __builtin_amdgcn_s_setprio(0); \
  } while (0)

#define GROUPK(BUFL, T) do { \
    LDAK(BUFL, 0, a0); LDBK(BUFL, 0, b0); \
    LDAK(BUFL, 1, a1); \
    if ((T) + 1 < NT) { STAGEK((BUFL) ^ 1, 1, 2, (T) + 1); STAGEK((BUFL) ^ 1, 1, 3, (T) + 1); } \
    PHK(a0, b0, 0, 0); \
    BARX(); \
    LDBK(BUFL, 1, b1); \
    PHK(a1, b0, 1, 0); \
    BARX(); \
    if ((T) + 2 < NT) { STAGEK(BUFL, 0, 0, (T) + 2); STAGEK(BUFL, 0, 1, (T) + 2); \
                        STAGEK(BUFL, 0, 2, (T) + 2); STAGEK(BUFL, 0, 3, (T) + 2); } \
    PHK(a1, b1, 1, 1); \
    BARX(); \
    if ((T) + 2 < NT) { STAGEK(BUFL, 1, 0, (T) + 2); STAGEK(BUFL, 1, 1, (T) + 2); } \
    PHK(a0, b1, 0, 1); \
    SB(); \
    if ((T) + 1 < NT) { \
      if ((T) + 1 == NT - 1) { asm volatile("s_waitcnt vmcnt(0)" ::: "memory"); } \
      else                   { asm volatile("s_waitcnt vmcnt(6)" ::: "memory"); } \
    } \
    __builtin_amdgcn_s_barrier(); \
    SB(); \
  } while (0)

template <int OM>
__device__ __forceinline__ void gemm128_body(
    char* ldsb, const unsigned short* __restrict__ Ab,
    const unsigned short* __restrict__ Bb,
    float* __restrict__ Cf, unsigned short* __restrict__ Ch, long cb,
    int NT, int ldA, int ldB, int ldC, int bm0, int bn0, float alpha) {
  const int tid = threadIdx.x, lane = tid & 63, wid = tid >> 6;
  const int wm = wid >> 1, wn = wid & 1;
  const int fr = lane & 15, fq = lane >> 4;

  const int sl0 = ((fq ^ (fr & 7)) << 4);
  const int sl1 = (((4 + fq) ^ (fr & 7)) << 4);
  const int arow = fr << 7;

  const int srow = tid >> 3;                       // [0,32)
  const int scsw = ((tid & 7) ^ (srow & 7)) << 3;  // inverse-swizzled global col

  f32x4 acc[4][4];
#pragma unroll
  for (int m = 0; m < 4; m++)
#pragma unroll
    for (int n = 0; n < 4; n++)
#pragma unroll
      for (int r = 0; r < 4; r++) acc[m][n][r] = 0.f;

  f16x8 a0[2][2], a1[2][2], b0[2][2], b1[2][2];

  STAGEK(0, 0, 0, 0); STAGEK(0, 0, 1, 0); STAGEK(0, 0, 2, 0); STAGEK(0, 0, 3, 0);
  STAGEK(0, 1, 0, 0); STAGEK(0, 1, 1, 0); STAGEK(0, 1, 2, 0); STAGEK(0, 1, 3, 0);
  STAGEK(1, 0, 0, 1); STAGEK(1, 0, 1, 1); STAGEK(1, 0, 2, 1); STAGEK(1, 0, 3, 1);
  STAGEK(1, 1, 0, 1); STAGEK(1, 1, 1, 1);
  asm volatile("s_waitcnt vmcnt(6)" ::: "memory");
  __builtin_amdgcn_s_barrier();
  SB();

  for (int t = 0; t < NT; t += 2) {
    GROUPK(0, t);
    GROUPK(1, t + 1);
  }

#pragma unroll
  for (int mh = 0; mh < 2; mh++)
#pragma unroll
    for (int mm = 0; mm < 2; mm++)
#pragma unroll
      for (int nh = 0; nh < 2; nh++)
#pragma unroll
        for (int nn = 0; nn < 2; nn++) {
          const int col = bn0 + wn * 64 + nh * 32 + nn * 16 + fr;
#pragma unroll
          for (int r = 0; r < 4; r++) {
            const long row = (long)bm0 + wm * 64 + mh * 32 + mm * 16 + fq * 4 + r;
            const long ci = cb + row * ldC + col;
            const float vv = acc[mh * 2 + mm][nh * 2 + nn][r] * alpha;
            if constexpr (OM == 0) Cf[ci] = vv;
            else                   Ch[ci] = f2h(vv);
          }
        }
}

// Standalone wrapper. CAUSAL: 0 none, 1 = skip bn0>bm0 (scores),
// 2 = K-limit NT=(bm0+128)/64 (P-contraction; NT even, >=2).
template <int OM, int CAUSAL>
__global__ __launch_bounds__(256, 2) void gemm128(
    const unsigned short* __restrict__ A, const unsigned short* __restrict__ B,
    float* __restrict__ Cf, unsigned short* __restrict__ Ch,
    int K, long sAb, long sBb, long sCb,
    int ldA, int ldB, int ldC, float alpha) {
  __shared__ __align__(16) char ldsarr[65536];
  const int bm0 = blockIdx.x * 128;
  const int bn0 = blockIdx.y * 128;
  if (CAUSAL == 1 && bn0 > bm0) return;  // fully masked; never read later
  const int z = blockIdx.z;
  int NT = K >> 6;
  if (CAUSAL == 2) NT = (bm0 + 128) >> 6;  // even; >=2
  gemm128_body<OM>(ldsarr, A + (long)z * sAb, B + (long)z * sBb,
                   Cf, Ch, (long)z * sCb, NT, ldA, ldB, ldC, bm0, bn0, alpha);
}

// Merged dispatch A: MT = Wk^T*Wq fold (z=0) || G = Wo*Wv fold (z=1).
// MT[f][e] = sum_d wkT[f][d]*wqT[e][d]   (= M[e,f], scores = x M x^T)
// G [i][e] = sum_j wo16[i][j]*wvT[e][j]  (out = P x G^T contraction)
// 512 blocks = full fill. All operands [2048][2048] fp16 K-contig.
__global__ __launch_bounds__(256, 2) void k_mt_g(
    const unsigned short* __restrict__ wkT, const unsigned short* __restrict__ wqT,
    const unsigned short* __restrict__ wo16, const unsigned short* __restrict__ wvT,
    unsigned short* __restrict__ MT, unsigned short* __restrict__ G) {
  __shared__ __align__(16) char ldsarr[65536];
  const int bm0 = blockIdx.x * 128;
  const int bn0 = blockIdx.y * 128;
  if (blockIdx.z == 0)
    gemm128_body<1>(ldsarr, wkT, wqT, nullptr, MT, 0L, DM >> 6, DM, DM, DM, bm0, bn0, 1.0f);
  else
    gemm128_body<1>(ldsarr, wo16, wvT, nullptr, G, 0L, DM >> 6, DM, DM, DM, bm0, bn0, 1.0f);
}

// Merged dispatch B: y = x*(MT)^T (z=0) || uT = G*x^T (z=1). 1024 blocks.
// y [s][f] = sum_e x16[s][e]*MT[f][e]   [4096][2048]
// uT[i][t] = sum_e G[i][e]*x16[t][e]    [2048][4096]
__global__ __launch_bounds__(256, 2) void k_y_ut(
    const unsigned short* __restrict__ x16, const unsigned short* __restrict__ MT,
    const unsigned short* __restrict__ G,
    unsigned short* __restrict__ y, unsigned short* __restrict__ uT) {
  __shared__ __align__(16) char ldsarr[65536];
  if (blockIdx.z == 0) {
    const int bm0 = blockIdx.x * 128;   // s: 32
    const int bn0 = blockIdx.y * 128;   // f: 16
    gemm128_body<1>(ldsarr, x16, MT, nullptr, y, 0L, DM >> 6, DM, DM, DM, bm0, bn0, 1.0f);
  } else {
    const int bm0 = blockIdx.y * 128;   // i: 16
    const int bn0 = blockIdx.x * 128;   // t: 32
    gemm128_body<1>(ldsarr, G, x16, nullptr, uT, 0L, DM >> 6, DM, DM, BSZ, bm0, bn0, 1.0f);
  }
}

// ---- causal row softmax: scores fp16 [NB*SQ][SQ] -> probs fp16, zeros t>s.
__global__ __launch_bounds__(256) void softmax_causal(const unsigned short* __restrict__ sc,
                                                      unsigned short* __restrict__ pr) {
  const int row = blockIdx.x;       // b*SQ + s
  const int s = row & (SQ - 1);
  const long base = (long)row * SQ;
  const int n = s + 1;              // valid prefix length
  const int tid = threadIdx.x;
  const int lane = tid & 63;
  const int wv = tid >> 6;
  const int e0 = tid * 8;
  __shared__ float red[4];

  union { uint4 u4; unsigned short us[8]; } in, ou;
  in.u4 = *(const uint4*)&sc[base + e0];

  float v[8];
  float mx = -3.0e38f;
#pragma unroll
  for (int j = 0; j < 8; j++) {
    v[j] = (e0 + j < n) ? h2f(in.us[j]) : -3.0e38f;  // mask BEFORE use
    mx = fmaxf(mx, v[j]);
  }
#pragma unroll
  for (int o = 32; o >= 1; o >>= 1) mx = fmaxf(mx, __shfl_xor(mx, o));
  if (lane == 0) red[wv] = mx;
  __syncthreads();
  mx = fmaxf(fmaxf(red[0], red[1]), fmaxf(red[2], red[3]));
  __syncthreads();

  float sum = 0.f;
#pragma unroll
  for (int j = 0; j < 8; j++) {
    v[j] = (e0 + j < n) ? __expf(v[j] - mx) : 0.f;
    sum += v[j];
  }
#pragma unroll
  for (int o = 32; o >= 1; o >>= 1) sum += __shfl_xor(sum, o);
  if (lane == 0) red[wv] = sum;
  __syncthreads();
  const float inv = 1.f / (red[0] + red[1] + red[2] + red[3]);
#pragma unroll
  for (int j = 0; j < 8; j++) ou.us[j] = (e0 + j < n) ? f2h(v[j] * inv) : (unsigned short)0;
  *(uint4*)&pr[base + e0] = ou.u4;
}

extern "C" void kernel_launch(void* const* d_in, const int* in_sizes, int n_in,
                              void* d_out, int out_size, void* d_ws, size_t ws_size,
                              hipStream_t stream) {
  (void)in_sizes; (void)n_in; (void)out_size; (void)ws_size;
  const float* x  = (const float*)d_in[0];
  // d_in[1] = mask: exactly causal-additive(-1e9) -> implemented structurally.
  const float* Wq = (const float*)d_in[2];
  const float* Wk = (const float*)d_in[3];
  const float* Wv = (const float*)d_in[4];
  const float* Wo = (const float*)d_in[5];
  float* out = (float*)d_out;

  const long ELx = (long)BSZ * DM;  // 8,388,608
  const long ELw = (long)DM * DM;   // 4,194,304

  char* ws = (char*)d_ws;
  size_t off = 0;
  auto take = [&](size_t bytes) { void* p = ws + off; off += bytes; return p; };

  unsigned short* x16  = (unsigned short*)take(ELx * 2);  // dead after k_y_ut
  unsigned short* wqT  = (unsigned short*)take(ELw * 2);  // dead after k_mt_g
  unsigned short* wkT  = (unsigned short*)take(ELw * 2);  // dead after k_mt_g
  unsigned short* wvT  = (unsigned short*)take(ELw * 2);  // dead after k_mt_g
  unsigned short* wo16 = (unsigned short*)take(ELw * 2);  // dead after k_mt_g
  unsigned short* MT   = (unsigned short*)take(ELw * 2);  // dead after k_y_ut
  unsigned short* G    = (unsigned short*)take(ELw * 2);  // dead after k_y_ut
  unsigned short* y    = (unsigned short*)take(ELx * 2);  // dead after scores
  unsigned short* uT   = (unsigned short*)take(ELx * 2);  // live till out
  unsigned short* probs = (unsigned short*)take((long)NB * SQ * SQ * 2);
  // scores (16 MiB = NB*SQ*SQ fp16) aliases wqT∪wkT exactly (both dead after
  // k_mt_g; scores written two dispatches later — stream-ordered).
  unsigned short* scores = wqT;

  const int n4x = (int)(ELx / 4), n4w = (int)(ELw / 4);
  cast_x_wo<<<dim3((n4x + n4w + 255) / 256), 256, 0, stream>>>(
      (const float4*)x, (const float4*)Wo, (ushort4*)x16, (ushort4*)wo16, n4x, n4w);
  cast_t<<<dim3(DM / 64, DM / 64, 3), 256, 0, stream>>>(
      Wq, Wk, Wv, wqT, wkT, wvT);

  const float scale = 0.08838834764831845f;  // 1/sqrt(128)

  // MT = Wk^T*Wq || G = Wo*Wv    [2048x2048 each], 512 blocks (full fill)
  k_mt_g<<<dim3(DM / 128, DM / 128, 2), 256, 0, stream>>>(
      wkT, wqT, wo16, wvT, MT, G);
  // y = x*M || uT = G*x^T        1024 blocks (2 full rounds)
  k_y_ut<<<dim3(BSZ / 128, DM / 128, 2), 256, 0, stream>>>(
      x16, MT, G, y, uT);
  // scores[b][s][t] = scale * sum_f y[s,f]*x[t,f]   (fp16, causal block-skip)
  gemm128<1, 1><<<dim3(SQ / 128, SQ / 128, NB), 256, 0, stream>>>(
      y, x16, nullptr, scores, DM, (long)SQ * DM, (long)SQ * DM,
      (long)SQ * SQ, DM, DM, SQ, scale);

  softmax_causal<<<dim3(NB * SQ), 256, 0, stream>>>(scores, probs);

  // out[b*2048+s][i] = sum_t P_b[s,t] * uT[i][b*2048+t]  (fp32 out, K-limited)
  gemm128<0, 2><<<dim3(SQ / 128, DM / 128, NB), 256, 0, stream>>>(
      probs, uT, out, nullptr, SQ, (long)SQ * SQ, 2048L, (long)SQ * DM,
      SQ, BSZ, DM, 1.0f);
}